// Round 9
// baseline (164.293 us; speedup 1.0000x reference)
//
#include <hip/hip_runtime.h>
#include <hip/hip_cooperative_groups.h>

namespace cg = cooperative_groups;

// TT-embedding: voc_quant (32,32,32), emb_quant (8,8,16), ranks (1,8,8,1).
// out[n, pair*16+e2] = sum_r2 A[i0*32+i1][pair*8+r2] * c2[i2][r2*16+e2],
// A = first contraction in bf16 (1 MB, L2-resident).
//
// Ladder: 39.5 -> 38.1 (R5 one-wave/idx) -> 37.3 (R6 contig stores) -> 36.3
// (R8 bf16 A). Busy-time audit says main kernel ~21-23 us; residual ~10 us is
// two-launch + inter-kernel overhead. R9: single cooperative kernel
// (phase1 = A row per block, grid.sync, phase2 = 32 idx/block).

#define TT_A_BYTES (1024u * 512u * 2u)   // bf16 A
#define TT_G 16      // two-kernel fallback: indices per block
#define TT_GF 32     // fused: indices per block (1024 blocks x 32 = 32768)

typedef float f4 __attribute__((ext_vector_type(4)));

// ---------------- fused cooperative kernel ----------------
__global__ __launch_bounds__(256, 4) void tt_fused_kernel(
    const int* __restrict__ x,
    const float* __restrict__ c0,   // [32][8][8]
    const float* __restrict__ c1,   // [32][8][8][8]
    const float* __restrict__ c2,   // [32][8][16]
    unsigned short* A,              // [1024][512] bf16 (d_ws)
    float* __restrict__ out,        // [N][1024]
    int N)
{
    __shared__ float s0[64];
    __shared__ float s1[512];
    __shared__ float s2[4096];      // all of c2, 16 KB
    const int t = threadIdx.x;
    const int b = blockIdx.x;       // 0..1023 == i0*32+i1

    // ---- phase 1: compute A row b; overlap c2->LDS staging
    const int i0 = b >> 5;
    const int i1 = b & 31;
    if (t < 16)
        *reinterpret_cast<float4*>(s0 + t * 4) =
            *reinterpret_cast<const float4*>(c0 + i0 * 64 + t * 4);
    if (t < 128)
        *reinterpret_cast<float4*>(s1 + t * 4) =
            *reinterpret_cast<const float4*>(c1 + i1 * 512 + t * 4);
    #pragma unroll
    for (int i = 0; i < 4; ++i)
        *reinterpret_cast<float4*>(s2 + (i * 256 + t) * 4) =
            *reinterpret_cast<const float4*>(c2 + (i * 256 + t) * 4);
    __syncthreads();

    unsigned short* Arow = A + (size_t)b * 512;
    #pragma unroll
    for (int v = t; v < 512; v += 256) {
        const int pair = v >> 3;            // e0*8 + e1
        const int r2   = v & 7;
        const int e0   = pair >> 3;
        const int e1   = pair & 7;
        float acc = 0.f;
        #pragma unroll
        for (int r1 = 0; r1 < 8; ++r1)
            acc = fmaf(s0[e0 * 8 + r1], s1[r1 * 64 + e1 * 8 + r2], acc);
        unsigned int u = __float_as_uint(acc);              // RNE -> bf16
        Arow[v] = (unsigned short)((u + 0x7fffu + ((u >> 16) & 1u)) >> 16);
    }

    cg::this_grid().sync();         // A complete + visible device-wide

    // ---- phase 2: 32 indices per block, 8 per wave
    const int w = t >> 6;
    const int l = t & 63;
    const int prow = l >> 2;        // pair sub-index 0..15
    const int eg   = l & 3;         // e2 group
    const int nbase = b * TT_GF + w * 8;

    int flats[8];
    {
        const int4 xa = *reinterpret_cast<const int4*>(x + nbase);
        const int4 xb = *reinterpret_cast<const int4*>(x + nbase + 4);
        flats[0] = xa.x; flats[1] = xa.y; flats[2] = xa.z; flats[3] = xa.w;
        flats[4] = xb.x; flats[5] = xb.y; flats[6] = xb.z; flats[7] = xb.w;
    }

    uint4 abuf[2][4];               // 2-deep A pipeline; static idx (unrolled)
    {
        const unsigned short* Ar = A + (size_t)((flats[0] >> 5) & 1023) * 512;
        #pragma unroll
        for (int p = 0; p < 4; ++p)
            abuf[0][p] = *reinterpret_cast<const uint4*>(Ar + (prow + 16 * p) * 8);
    }

    #pragma unroll
    for (int g = 0; g < 8; ++g) {
        if (g < 7) {
            const unsigned short* Ar =
                A + (size_t)((flats[g + 1] >> 5) & 1023) * 512;
            #pragma unroll
            for (int p = 0; p < 4; ++p)
                abuf[(g + 1) & 1][p] =
                    *reinterpret_cast<const uint4*>(Ar + (prow + 16 * p) * 8);
        }

        const int flat = flats[g];
        const float* c2s = s2 + (flat & 31) * 128;
        f4 cv[8];
        #pragma unroll
        for (int r2 = 0; r2 < 8; ++r2)
            cv[r2] = *reinterpret_cast<const f4*>(c2s + r2 * 16 + eg * 4);

        f4* outp = reinterpret_cast<f4*>(out + (size_t)(nbase + g) * 1024);
        const bool pad = (flat == 0);

        #pragma unroll
        for (int p = 0; p < 4; ++p) {
            const uint4 av = abuf[g & 1][p];
            float ax[8];
            ax[0] = __uint_as_float(av.x << 16);
            ax[1] = __uint_as_float(av.x & 0xffff0000u);
            ax[2] = __uint_as_float(av.y << 16);
            ax[3] = __uint_as_float(av.y & 0xffff0000u);
            ax[4] = __uint_as_float(av.z << 16);
            ax[5] = __uint_as_float(av.z & 0xffff0000u);
            ax[6] = __uint_as_float(av.w << 16);
            ax[7] = __uint_as_float(av.w & 0xffff0000u);

            f4 o = {0.f, 0.f, 0.f, 0.f};
            #pragma unroll
            for (int r2 = 0; r2 < 8; ++r2) {
                o.x = fmaf(ax[r2], cv[r2].x, o.x);
                o.y = fmaf(ax[r2], cv[r2].y, o.y);
                o.z = fmaf(ax[r2], cv[r2].z, o.z);
                o.w = fmaf(ax[r2], cv[r2].w, o.w);
            }
            if (pad) o = (f4){0.f, 0.f, 0.f, 0.f};          // padding_idx
            __builtin_nontemporal_store(o, outp + (l + 64 * p));
        }
    }
}

// ---------------- two-kernel fallback (R8, known-good 36.3 us) ----------------
__global__ __launch_bounds__(256) void tt_precomp_kernel(
    const float* __restrict__ c0,
    const float* __restrict__ c1,
    unsigned short* __restrict__ A)
{
    __shared__ float s0[64];
    __shared__ float s1[512];
    const int i0 = blockIdx.x >> 5;
    const int i1 = blockIdx.x & 31;
    const int t  = threadIdx.x;

    if (t < 16)
        *reinterpret_cast<float4*>(s0 + t * 4) =
            *reinterpret_cast<const float4*>(c0 + i0 * 64 + t * 4);
    if (t < 128)
        *reinterpret_cast<float4*>(s1 + t * 4) =
            *reinterpret_cast<const float4*>(c1 + i1 * 512 + t * 4);
    __syncthreads();

    unsigned short* Ar = A + (size_t)blockIdx.x * 512;
    #pragma unroll
    for (int v = t; v < 512; v += 256) {
        const int pair = v >> 3;
        const int r2   = v & 7;
        const int e0   = pair >> 3;
        const int e1   = pair & 7;
        float acc = 0.f;
        #pragma unroll
        for (int r1 = 0; r1 < 8; ++r1)
            acc = fmaf(s0[e0 * 8 + r1], s1[r1 * 64 + e1 * 8 + r2], acc);
        unsigned int u = __float_as_uint(acc);
        Ar[v] = (unsigned short)((u + 0x7fffu + ((u >> 16) & 1u)) >> 16);
    }
}

__global__ __launch_bounds__(256) void tt_emb_kernel(
    const int* __restrict__ x,
    const unsigned short* __restrict__ A,
    const float* __restrict__ c2,
    float* __restrict__ out,
    int N)
{
    __shared__ float s2[4096];
    const int t = threadIdx.x;

    #pragma unroll
    for (int i = 0; i < 4; ++i)
        *reinterpret_cast<float4*>(s2 + (i * 256 + t) * 4) =
            *reinterpret_cast<const float4*>(c2 + (i * 256 + t) * 4);
    __syncthreads();

    const int w = t >> 6;
    const int l = t & 63;
    const int prow = l >> 2;
    const int eg   = l & 3;
    const int nbase = blockIdx.x * TT_G + w * 4;

    const int4 xv = *reinterpret_cast<const int4*>(x + nbase);
    const int flats[4] = {xv.x, xv.y, xv.z, xv.w};

    uint4 abuf[2][4];
    {
        const unsigned short* Ar = A + (size_t)((flats[0] >> 5) & 1023) * 512;
        #pragma unroll
        for (int p = 0; p < 4; ++p)
            abuf[0][p] = *reinterpret_cast<const uint4*>(Ar + (prow + 16 * p) * 8);
    }

    #pragma unroll
    for (int g = 0; g < 4; ++g) {
        if (g < 3) {
            const unsigned short* Ar = A + (size_t)((flats[g + 1] >> 5) & 1023) * 512;
            #pragma unroll
            for (int p = 0; p < 4; ++p)
                abuf[(g + 1) & 1][p] =
                    *reinterpret_cast<const uint4*>(Ar + (prow + 16 * p) * 8);
        }

        const int flat = flats[g];
        const float* c2s = s2 + (flat & 31) * 128;
        f4 cv[8];
        #pragma unroll
        for (int r2 = 0; r2 < 8; ++r2)
            cv[r2] = *reinterpret_cast<const f4*>(c2s + r2 * 16 + eg * 4);

        f4* outp = reinterpret_cast<f4*>(out + (size_t)(nbase + g) * 1024);
        const bool pad = (flat == 0);

        #pragma unroll
        for (int p = 0; p < 4; ++p) {
            const uint4 av = abuf[g & 1][p];
            float ax[8];
            ax[0] = __uint_as_float(av.x << 16);
            ax[1] = __uint_as_float(av.x & 0xffff0000u);
            ax[2] = __uint_as_float(av.y << 16);
            ax[3] = __uint_as_float(av.y & 0xffff0000u);
            ax[4] = __uint_as_float(av.z << 16);
            ax[5] = __uint_as_float(av.z & 0xffff0000u);
            ax[6] = __uint_as_float(av.w << 16);
            ax[7] = __uint_as_float(av.w & 0xffff0000u);

            f4 o = {0.f, 0.f, 0.f, 0.f};
            #pragma unroll
            for (int r2 = 0; r2 < 8; ++r2) {
                o.x = fmaf(ax[r2], cv[r2].x, o.x);
                o.y = fmaf(ax[r2], cv[r2].y, o.y);
                o.z = fmaf(ax[r2], cv[r2].z, o.z);
                o.w = fmaf(ax[r2], cv[r2].w, o.w);
            }
            if (pad) o = (f4){0.f, 0.f, 0.f, 0.f};
            __builtin_nontemporal_store(o, outp + (l + 64 * p));
        }
    }
}

// ---- last-resort fallback (ws too small): round-1 LDS kernel
__global__ __launch_bounds__(256) void tt_emb_lds_kernel(
    const int* __restrict__ x,
    const float* __restrict__ c0,
    const float* __restrict__ c1,
    const float* __restrict__ c2,
    float* __restrict__ out)
{
    const int n = blockIdx.x;
    const int t = threadIdx.x;

    __shared__ float s0[64];
    __shared__ float s1[512];
    __shared__ float s2[128];

    const int flat = x[n];
    const int i0 = (flat >> 10) & 31;
    const int i1 = (flat >> 5) & 31;
    const int i2 = flat & 31;

    if (t < 64)  s0[t] = c0[i0 * 64 + t];
    s1[t]        = c1[i1 * 512 + t];
    s1[t + 256]  = c1[i1 * 512 + 256 + t];
    if (t < 128) s2[t] = c2[i2 * 128 + t];
    __syncthreads();

    const int e0  = t >> 5;
    const int e1  = (t >> 2) & 7;
    const int e2b = (t & 3) << 2;

    float tmp[8] = {0.f, 0.f, 0.f, 0.f, 0.f, 0.f, 0.f, 0.f};
    #pragma unroll
    for (int r1 = 0; r1 < 8; ++r1) {
        const float a = s0[e0 * 8 + r1];
        #pragma unroll
        for (int r2 = 0; r2 < 8; ++r2)
            tmp[r2] = fmaf(a, s1[r1 * 64 + e1 * 8 + r2], tmp[r2]);
    }

    float res[4];
    #pragma unroll
    for (int q = 0; q < 4; ++q) {
        float acc = 0.f;
        #pragma unroll
        for (int r2 = 0; r2 < 8; ++r2)
            acc = fmaf(tmp[r2], s2[r2 * 16 + e2b + q], acc);
        res[q] = acc;
    }

    if (flat == 0) { res[0] = res[1] = res[2] = res[3] = 0.f; }

    *reinterpret_cast<float4*>(out + (size_t)n * 1024 + (size_t)t * 4) =
        make_float4(res[0], res[1], res[2], res[3]);
}

extern "C" void kernel_launch(void* const* d_in, const int* in_sizes, int n_in,
                              void* d_out, int out_size, void* d_ws, size_t ws_size,
                              hipStream_t stream) {
    const int*   x  = (const int*)d_in[0];     // 32768 indices
    const float* c0 = (const float*)d_in[1];   // 2048 floats
    const float* c1 = (const float*)d_in[2];   // 16384 floats
    const float* c2 = (const float*)d_in[3];   // 4096 floats
    float* out = (float*)d_out;                // 33554432 fp32

    const int N = in_sizes[0];                 // 32768

    if (ws_size >= TT_A_BYTES && N == 1024 * TT_GF) {
        unsigned short* A = (unsigned short*)d_ws;
        void* args[] = {(void*)&x, (void*)&c0, (void*)&c1, (void*)&c2,
                        (void*)&A, (void*)&out, (void*)&N};
        hipError_t e = hipLaunchCooperativeKernel(
            (const void*)tt_fused_kernel, dim3(1024), dim3(256), args, 0, stream);
        if (e == hipSuccess) return;
        // fall through to two-kernel path on any cooperative-launch failure
        tt_precomp_kernel<<<1024, 256, 0, stream>>>(c0, c1, A);
        tt_emb_kernel<<<N / TT_G, 256, 0, stream>>>(x, A, c2, out, N);
    } else if (ws_size >= TT_A_BYTES && (N % TT_G) == 0) {
        unsigned short* A = (unsigned short*)d_ws;
        tt_precomp_kernel<<<1024, 256, 0, stream>>>(c0, c1, A);
        tt_emb_kernel<<<N / TT_G, 256, 0, stream>>>(x, A, c2, out, N);
    } else {
        tt_emb_lds_kernel<<<N, 256, 0, stream>>>(x, c0, c1, c2, out);
    }
}

// Round 10
// 34.410 us; speedup vs baseline: 4.7745x; 4.7745x over previous
//
#include <hip/hip_runtime.h>

// TT-embedding: voc_quant (32,32,32), emb_quant (8,8,16), ranks (1,8,8,1).
// out[n, pair*16+e2] = sum_r2 A[i0*32+i1][pair*8+r2] * c2[i2][r2*16+e2],
// A = first contraction in bf16 (1 MB, L2-resident).
//
// Ladder: 39.5 -> 38.1 (R5 one-wave/idx) -> 37.3 (R6 contig stores) -> 36.3
// (R8 bf16 A). R9 coop fusion refuted (149 us: XCD-L2 invalidation after
// grid.sync). R10: long-lived waves — 16 idx/wave (512 blocks, 2/CU), regular
// stores (nt was -0.3 in R6/R7). Prologue/ramp amortized 4x.

#define TT_A_BYTES (1024u * 512u * 2u)   // bf16 A

typedef float f4 __attribute__((ext_vector_type(4)));

// ---- Kernel 1: A[i0][i1][pair*8+r2] = bf16( sum_r1 c0[i0][e0][r1] * c1[i1][r1][e1][r2] )
__global__ __launch_bounds__(256) void tt_precomp_kernel(
    const float* __restrict__ c0,   // [32][8][8]
    const float* __restrict__ c1,   // [32][8][8][8]
    unsigned short* __restrict__ A) // [1024][512] bf16
{
    __shared__ float s0[64];
    __shared__ float s1[512];
    const int i0 = blockIdx.x >> 5;
    const int i1 = blockIdx.x & 31;
    const int t  = threadIdx.x;

    if (t < 16)
        *reinterpret_cast<float4*>(s0 + t * 4) =
            *reinterpret_cast<const float4*>(c0 + i0 * 64 + t * 4);
    if (t < 128)
        *reinterpret_cast<float4*>(s1 + t * 4) =
            *reinterpret_cast<const float4*>(c1 + i1 * 512 + t * 4);
    __syncthreads();

    unsigned short* Ar = A + (size_t)blockIdx.x * 512;
    #pragma unroll
    for (int v = t; v < 512; v += 256) {
        const int pair = v >> 3;            // e0*8 + e1
        const int r2   = v & 7;
        const int e0   = pair >> 3;
        const int e1   = pair & 7;
        float acc = 0.f;
        #pragma unroll
        for (int r1 = 0; r1 < 8; ++r1)
            acc = fmaf(s0[e0 * 8 + r1], s1[r1 * 64 + e1 * 8 + r2], acc);
        unsigned int u = __float_as_uint(acc);              // RNE -> bf16
        Ar[v] = (unsigned short)((u + 0x7fffu + ((u >> 16) & 1u)) >> 16);
    }
}

// ---- Kernel 2: one wave per index, IPW indices per wave, regular stores.
template<int IPW>
__global__ __launch_bounds__(256) void tt_emb_kernel(
    const int* __restrict__ x,
    const unsigned short* __restrict__ A,  // [1024][512] bf16
    const float* __restrict__ c2,          // [32][8][16] = 4096 floats
    float* __restrict__ out,               // [N][1024]
    int N)
{
    __shared__ float s2[4096];      // all of c2, 16 KB
    const int t = threadIdx.x;

    #pragma unroll
    for (int i = 0; i < 4; ++i)
        *reinterpret_cast<float4*>(s2 + (i * 256 + t) * 4) =
            *reinterpret_cast<const float4*>(c2 + (i * 256 + t) * 4);
    __syncthreads();

    const int w = t >> 6;               // wave id 0..3
    const int l = t & 63;               // lane
    const int prow = l >> 2;            // pair sub-index 0..15
    const int eg   = l & 3;             // e2 group
    const int nbase = blockIdx.x * (4 * IPW) + w * IPW;

    int flats[IPW];
    #pragma unroll
    for (int k = 0; k < IPW / 4; ++k) {
        const int4 xv = *reinterpret_cast<const int4*>(x + nbase + 4 * k);
        flats[4 * k]     = xv.x;
        flats[4 * k + 1] = xv.y;
        flats[4 * k + 2] = xv.z;
        flats[4 * k + 3] = xv.w;
    }

    uint4 abuf[2][4];                   // 2-deep A pipeline; static idx (unrolled)
    {
        const unsigned short* Ar = A + (size_t)((flats[0] >> 5) & 1023) * 512;
        #pragma unroll
        for (int p = 0; p < 4; ++p)
            abuf[0][p] = *reinterpret_cast<const uint4*>(Ar + (prow + 16 * p) * 8);
    }

    #pragma unroll
    for (int g = 0; g < IPW; ++g) {
        if (g < IPW - 1) {   // issue next index's A loads before using current
            const unsigned short* Ar =
                A + (size_t)((flats[g + 1] >> 5) & 1023) * 512;
            #pragma unroll
            for (int p = 0; p < 4; ++p)
                abuf[(g + 1) & 1][p] =
                    *reinterpret_cast<const uint4*>(Ar + (prow + 16 * p) * 8);
        }

        const int flat = flats[g];
        const float* c2s = s2 + (flat & 31) * 128;
        f4 cv[8];
        #pragma unroll
        for (int r2 = 0; r2 < 8; ++r2)
            cv[r2] = *reinterpret_cast<const f4*>(c2s + r2 * 16 + eg * 4);

        f4* outp = reinterpret_cast<f4*>(out + (size_t)(nbase + g) * 1024);
        const bool pad = (flat == 0);

        #pragma unroll
        for (int p = 0; p < 4; ++p) {
            const uint4 av = abuf[g & 1][p];
            float ax[8];
            ax[0] = __uint_as_float(av.x << 16);
            ax[1] = __uint_as_float(av.x & 0xffff0000u);
            ax[2] = __uint_as_float(av.y << 16);
            ax[3] = __uint_as_float(av.y & 0xffff0000u);
            ax[4] = __uint_as_float(av.z << 16);
            ax[5] = __uint_as_float(av.z & 0xffff0000u);
            ax[6] = __uint_as_float(av.w << 16);
            ax[7] = __uint_as_float(av.w & 0xffff0000u);

            f4 o = {0.f, 0.f, 0.f, 0.f};
            #pragma unroll
            for (int r2 = 0; r2 < 8; ++r2) {
                o.x = fmaf(ax[r2], cv[r2].x, o.x);
                o.y = fmaf(ax[r2], cv[r2].y, o.y);
                o.z = fmaf(ax[r2], cv[r2].z, o.z);
                o.w = fmaf(ax[r2], cv[r2].w, o.w);
            }
            if (pad) o = (f4){0.f, 0.f, 0.f, 0.f};          // padding_idx
            outp[l + 64 * p] = o;       // contiguous 1 KB per wave store
        }
    }
}

// ---- last-resort fallback (ws too small): round-1 LDS kernel
__global__ __launch_bounds__(256) void tt_emb_lds_kernel(
    const int* __restrict__ x,
    const float* __restrict__ c0,
    const float* __restrict__ c1,
    const float* __restrict__ c2,
    float* __restrict__ out)
{
    const int n = blockIdx.x;
    const int t = threadIdx.x;

    __shared__ float s0[64];
    __shared__ float s1[512];
    __shared__ float s2[128];

    const int flat = x[n];
    const int i0 = (flat >> 10) & 31;
    const int i1 = (flat >> 5) & 31;
    const int i2 = flat & 31;

    if (t < 64)  s0[t] = c0[i0 * 64 + t];
    s1[t]        = c1[i1 * 512 + t];
    s1[t + 256]  = c1[i1 * 512 + 256 + t];
    if (t < 128) s2[t] = c2[i2 * 128 + t];
    __syncthreads();

    const int e0  = t >> 5;
    const int e1  = (t >> 2) & 7;
    const int e2b = (t & 3) << 2;

    float tmp[8] = {0.f, 0.f, 0.f, 0.f, 0.f, 0.f, 0.f, 0.f};
    #pragma unroll
    for (int r1 = 0; r1 < 8; ++r1) {
        const float a = s0[e0 * 8 + r1];
        #pragma unroll
        for (int r2 = 0; r2 < 8; ++r2)
            tmp[r2] = fmaf(a, s1[r1 * 64 + e1 * 8 + r2], tmp[r2]);
    }

    float res[4];
    #pragma unroll
    for (int q = 0; q < 4; ++q) {
        float acc = 0.f;
        #pragma unroll
        for (int r2 = 0; r2 < 8; ++r2)
            acc = fmaf(tmp[r2], s2[r2 * 16 + e2b + q], acc);
        res[q] = acc;
    }

    if (flat == 0) { res[0] = res[1] = res[2] = res[3] = 0.f; }

    *reinterpret_cast<float4*>(out + (size_t)n * 1024 + (size_t)t * 4) =
        make_float4(res[0], res[1], res[2], res[3]);
}

extern "C" void kernel_launch(void* const* d_in, const int* in_sizes, int n_in,
                              void* d_out, int out_size, void* d_ws, size_t ws_size,
                              hipStream_t stream) {
    const int*   x  = (const int*)d_in[0];     // 32768 indices
    const float* c0 = (const float*)d_in[1];   // 2048 floats
    const float* c1 = (const float*)d_in[2];   // 16384 floats
    const float* c2 = (const float*)d_in[3];   // 4096 floats
    float* out = (float*)d_out;                // 33554432 fp32

    const int N = in_sizes[0];                 // 32768

    if (ws_size >= TT_A_BYTES && (N % 64) == 0) {
        unsigned short* A = (unsigned short*)d_ws;
        tt_precomp_kernel<<<1024, 256, 0, stream>>>(c0, c1, A);
        tt_emb_kernel<16><<<N / 64, 256, 0, stream>>>(x, A, c2, out, N);  // 16 idx/wave
    } else if (ws_size >= TT_A_BYTES && (N % 16) == 0) {
        unsigned short* A = (unsigned short*)d_ws;
        tt_precomp_kernel<<<1024, 256, 0, stream>>>(c0, c1, A);
        tt_emb_kernel<4><<<N / 16, 256, 0, stream>>>(x, A, c2, out, N);   // R8 geometry
    } else {
        tt_emb_lds_kernel<<<N, 256, 0, stream>>>(x, c0, c1, c2, out);
    }
}